// Round 1
// baseline (391.127 us; speedup 1.0000x reference)
//
#include <hip/hip_runtime.h>
#include <stdint.h>

#define B_ 2
#define T_ 2048
#define DM 2048
#define NH 16
#define NKV 8
#define HD 128
#define NQKV 4096
#define SCALE_ 0.08838834764831845f  // 1/sqrt(128)

typedef float fx4 __attribute__((ext_vector_type(4)));
typedef __bf16 bfx8 __attribute__((ext_vector_type(8)));
typedef unsigned short u16;
typedef unsigned int u32;

typedef __attribute__((address_space(1))) const void gas_t;
typedef __attribute__((address_space(3))) void las_t;

__device__ __forceinline__ u16 f2bf(float f) {
  u32 u = __float_as_uint(f);
  u = (u + 0x7fffu + ((u >> 16) & 1u)) >> 16;
  return (u16)u;
}

__device__ __forceinline__ float bf2f(u16 b) {
  return __uint_as_float(((u32)b) << 16);
}

// async global->LDS, 16B per lane; lds arg must be segbase + lane*16
__device__ __forceinline__ void stage16(const void* g, void* l) {
  __builtin_amdgcn_global_load_lds((gas_t*)(uintptr_t)g, (las_t*)(uintptr_t)l,
                                   16, 0, 0);
}

// ---------------- fp32 -> bf16 convert ----------------
__global__ void k_cvt(const float* __restrict__ in, u16* __restrict__ out, int n) {
  int i = (blockIdx.x * blockDim.x + threadIdx.x) * 4;
  if (i + 3 < n) {
    float4 v = *(const float4*)(in + i);
    u32 w0 = (u32)f2bf(v.x) | ((u32)f2bf(v.y) << 16);
    u32 w1 = (u32)f2bf(v.z) | ((u32)f2bf(v.w) << 16);
    *(uint2*)(out + i) = make_uint2(w0, w1);
  }
}

// ---------------- bf16 GEMM: C[M][N] = A[M][K] * B[N][K]^T ----------------
// 128x128 tile, BK=32, 256 threads = 4 waves (2x2 of 64x64)
template <bool OUT_F32>
__global__ __launch_bounds__(256, 2) void k_gemm(const u16* __restrict__ A,
                                                 const u16* __restrict__ Bm,
                                                 void* __restrict__ Cv,
                                                 const float* __restrict__ bias,
                                                 int M, int N, int K) {
  __shared__ __align__(16) u16 As[128 * 32];
  __shared__ __align__(16) u16 Bs[128 * 32];
  const int nbn = N >> 7;
  const int bm = blockIdx.x / nbn, bn = blockIdx.x % nbn;
  const int tid = threadIdx.x;
  const int w = tid >> 6, lane = tid & 63;
  const int wr = w >> 1, wc = w & 1;
  const int lr = lane & 15, lg = lane >> 4;
  const u16* Ab = A + (size_t)bm * 128 * K;
  const u16* Bb = Bm + (size_t)bn * 128 * K;
  const int srow = lane >> 2, skc = (lane & 3) * 8;

  fx4 zero4 = {0.f, 0.f, 0.f, 0.f};
  fx4 acc[4][4];
#pragma unroll
  for (int m = 0; m < 4; m++)
#pragma unroll
    for (int n = 0; n < 4; n++) acc[m][n] = zero4;

  for (int k0 = 0; k0 < K; k0 += 32) {
#pragma unroll
    for (int t = 0; t < 2; t++) {
      int s = w + t * 4;  // 8 segments of 16 rows each
      stage16(Ab + (size_t)(s * 16 + srow) * K + k0 + skc, As + s * 512 + lane * 8);
      stage16(Bb + (size_t)(s * 16 + srow) * K + k0 + skc, Bs + s * 512 + lane * 8);
    }
    __syncthreads();
    bfx8 af[4], bfr[4];
#pragma unroll
    for (int m = 0; m < 4; m++)
      af[m] = *(const bfx8*)(As + (wr * 64 + m * 16 + lr) * 32 + lg * 8);
#pragma unroll
    for (int n = 0; n < 4; n++)
      bfr[n] = *(const bfx8*)(Bs + (wc * 64 + n * 16 + lr) * 32 + lg * 8);
#pragma unroll
    for (int m = 0; m < 4; m++)
#pragma unroll
      for (int n = 0; n < 4; n++)
        acc[m][n] = __builtin_amdgcn_mfma_f32_16x16x32_bf16(af[m], bfr[n], acc[m][n], 0, 0, 0);
    __syncthreads();
  }

  const int r0 = bm * 128 + wr * 64, c0 = bn * 128 + wc * 64;
#pragma unroll
  for (int m = 0; m < 4; m++) {
#pragma unroll
    for (int n = 0; n < 4; n++) {
      int c = c0 + n * 16 + lr;
#pragma unroll
      for (int i = 0; i < 4; i++) {
        int r = r0 + m * 16 + lg * 4 + i;
        if (OUT_F32) {
          ((float*)Cv)[(size_t)r * N + c] = acc[m][n][i] + bias[c];
        } else {
          ((u16*)Cv)[(size_t)r * N + c] = f2bf(acc[m][n][i]);
        }
      }
    }
  }
}

// ---------------- Q/K epilogue: rmsnorm + rope, relayout ----------------
// grid = B * 32(t64) * 24(16 q heads + 8 k heads); 256 thr; 4 thr/token
__global__ __launch_bounds__(256) void k_qkpost(const u16* __restrict__ qkv,
                                                const float* __restrict__ cosp,
                                                const float* __restrict__ sinp,
                                                const float* __restrict__ gq,
                                                const float* __restrict__ gk,
                                                u16* __restrict__ Qo,
                                                u16* __restrict__ Ko) {
  int bi = blockIdx.x;
  int hh = bi % 24;
  int t64 = (bi / 24) % 32;
  int b = bi / 768;
  int tid = threadIdx.x;
  int j = tid >> 2, p = tid & 3;
  int t = t64 * 64 + j;
  bool isq = hh < 16;
  int colbase = isq ? hh * 128 : 2048 + (hh - 16) * 128;
  const u16* src = qkv + ((size_t)(b * T_ + t)) * NQKV + colbase + p * 32;

  float xv[32];
#pragma unroll
  for (int c = 0; c < 4; c++) {
    uint4 raw = *(const uint4*)(src + c * 8);
    u32 wd[4] = {raw.x, raw.y, raw.z, raw.w};
#pragma unroll
    for (int q2 = 0; q2 < 4; q2++) {
      xv[c * 8 + q2 * 2 + 0] = __uint_as_float(wd[q2] << 16);
      xv[c * 8 + q2 * 2 + 1] = __uint_as_float(wd[q2] & 0xffff0000u);
    }
  }
  float ss = 0.f;
#pragma unroll
  for (int i = 0; i < 32; i++) ss += xv[i] * xv[i];
  ss += __shfl_xor(ss, 1);
  ss += __shfl_xor(ss, 2);
  float rinv = rsqrtf(ss * (1.0f / 128.0f) + 1e-6f);
  const float* g = isq ? gq : gk;
  const float* cr = cosp + (size_t)t * 128 + p * 32;
  const float* sr = sinp + (size_t)t * 128 + p * 32;

  float ov[32];
#pragma unroll
  for (int i = 0; i < 32; i++) {
    float y = xv[i] * rinv * g[p * 32 + i];
    float oth = __shfl_xor(y, 2);  // partner dim d^64
    float rot = (p < 2) ? -oth : oth;
    ov[i] = y * cr[i] + rot * sr[i];
  }

  // pack 32 bf16 -> 4 x uint4
  uint4 pk[4];
#pragma unroll
  for (int c = 0; c < 4; c++) {
    u32 wd[4];
#pragma unroll
    for (int q2 = 0; q2 < 4; q2++)
      wd[q2] = (u32)f2bf(ov[c * 8 + q2 * 2]) | ((u32)f2bf(ov[c * 8 + q2 * 2 + 1]) << 16);
    pk[c] = make_uint4(wd[0], wd[1], wd[2], wd[3]);
  }

  if (isq) {
    u16* dst = Qo + (((size_t)(b * NH + hh)) * T_ + t) * HD + p * 32;
#pragma unroll
    for (int c = 0; c < 4; c++) *(uint4*)(dst + c * 8) = pk[c];
  } else {
    int hk = hh - 16;
    u16* dstrow = Ko + (((size_t)(b * NKV + hk)) * T_ + t) * HD;
#pragma unroll
    for (int c = 0; c < 4; c++) {
      int C = p * 4 + c;
      int Cs = C ^ (t & 7);  // XOR swizzle, matches attn LDS read
      *(uint4*)(dstrow + Cs * 8) = pk[c];
    }
  }
}

// ---------------- V transpose: qkv[...,3072+] -> vt[b][hkv][d][t] ----------------
// grid = B * 32(t64) * 8(hkv)
__global__ __launch_bounds__(256) void k_vtr(const u16* __restrict__ qkv,
                                             u16* __restrict__ vt) {
  __shared__ __align__(16) u16 sm[128 * 64];
  int bi = blockIdx.x;
  int hv = bi & 7;
  int t64 = (bi >> 3) & 31;
  int b = bi >> 8;
  int tid = threadIdx.x;
#pragma unroll
  for (int it = 0; it < 4; it++) {
    int idx = tid + it * 256;  // chunk 0..1023
    int tok = idx >> 4, c = idx & 15;
    uint4 raw = *(const uint4*)(qkv + ((size_t)(b * T_ + t64 * 64 + tok)) * NQKV +
                                3072 + hv * 128 + c * 8);
    u32 wd[4] = {raw.x, raw.y, raw.z, raw.w};
#pragma unroll
    for (int q2 = 0; q2 < 4; q2++) {
      sm[(c * 8 + q2 * 2 + 0) * 64 + tok] = (u16)(wd[q2] & 0xffffu);
      sm[(c * 8 + q2 * 2 + 1) * 64 + tok] = (u16)(wd[q2] >> 16);
    }
  }
  __syncthreads();
  int d = tid >> 1, half = tid & 1;
  size_t ob = (((size_t)(b * NKV + hv)) * HD + d) * T_ + t64 * 64 + half * 32;
#pragma unroll
  for (int c = 0; c < 4; c++) {
    int cs = c ^ (d & 3);  // chunk swizzle within each 32-kv group
    u32 wd[4];
#pragma unroll
    for (int q2 = 0; q2 < 4; q2++) {
      u32 lo = sm[d * 64 + half * 32 + c * 8 + 2 * q2];
      u32 hi = sm[d * 64 + half * 32 + c * 8 + 2 * q2 + 1];
      wd[q2] = lo | (hi << 16);
    }
    *(uint4*)(vt + ob + cs * 8) = make_uint4(wd[0], wd[1], wd[2], wd[3]);
  }
}

// ---------------- flash attention (causal, GQA rep=2) ----------------
// grid = B * NH * (T/64); 4 waves, each 16 q rows; KV chunks of 32
__global__ __launch_bounds__(256, 2) void k_attn(const u16* __restrict__ Qg,
                                                 const u16* __restrict__ Kg,
                                                 const u16* __restrict__ Vg,
                                                 u16* __restrict__ Og) {
  __shared__ __align__(16) u16 Ks[32 * 128];
  __shared__ __align__(16) u16 Vs[128 * 32];
  __shared__ __align__(16) u16 Ps[4][16 * 32];
  const int bi = blockIdx.x;
  const int qt = bi & 31, h = (bi >> 5) & 15, b = bi >> 9;
  const int hkv = h >> 1;
  const int tid = threadIdx.x, w = tid >> 6, lane = tid & 63;
  const int lr = lane & 15, lg = lane >> 4;
  const int qr0 = qt * 64 + w * 16;

  const u16* qbase = Qg + (((size_t)(b * NH + h)) * T_ + qr0 + lr) * HD;
  bfx8 qf[4];
#pragma unroll
  for (int kk = 0; kk < 4; kk++) qf[kk] = *(const bfx8*)(qbase + kk * 32 + lg * 8);

  fx4 zero4 = {0.f, 0.f, 0.f, 0.f};
  fx4 o[8];
#pragma unroll
  for (int nf = 0; nf < 8; nf++) o[nf] = zero4;
  float m_i[4] = {-1e30f, -1e30f, -1e30f, -1e30f};
  float l_i[4] = {0.f, 0.f, 0.f, 0.f};

  const u16* kb = Kg + ((size_t)(b * NKV + hkv)) * T_ * HD;
  const u16* vb = Vg + ((size_t)(b * NKV + hkv)) * HD * T_;
  const int nch = qt * 2 + 2;

  for (int ch = 0; ch < nch; ch++) {
    const int kv0 = ch * 32;
#pragma unroll
    for (int t = 0; t < 2; t++) {
      int s = 2 * w + t;  // 8 segments each
      // K tile [32][128]: seg = 4 rows; lane: row 4s+lg, chunk lr (global pre-swizzled)
      stage16(kb + ((size_t)(kv0 + 4 * s + lg)) * HD + lr * 8, Ks + s * 512 + lane * 8);
      // V tile [128][32]: seg = 16 rows; lane: row 16s+(lane>>2), chunk lane&3
      stage16(vb + ((size_t)(16 * s + (lane >> 2))) * T_ + kv0 + (lane & 3) * 8,
              Vs + s * 512 + lane * 8);
    }
    __syncthreads();

    // S = Q K^T  (two 16-col frags over kv32)
    fx4 sa[2];
    sa[0] = zero4;
    sa[1] = zero4;
#pragma unroll
    for (int n = 0; n < 2; n++) {
      int trow = n * 16 + lr;
#pragma unroll
      for (int kk = 0; kk < 4; kk++) {
        int cs = (kk * 4 + lg) ^ (trow & 7);
        bfx8 kf = *(const bfx8*)(Ks + trow * 128 + cs * 8);
        sa[n] = __builtin_amdgcn_mfma_f32_16x16x32_bf16(qf[kk], kf, sa[n], 0, 0, 0);
      }
    }

    // mask + scale
    float pv0[4], pv1[4];
#pragma unroll
    for (int i = 0; i < 4; i++) {
      int r = qr0 + 4 * lg + i;
      float v0 = sa[0][i] * SCALE_;
      float v1 = sa[1][i] * SCALE_;
      pv0[i] = ((kv0 + lr) > r) ? -1e30f : v0;
      pv1[i] = ((kv0 + 16 + lr) > r) ? -1e30f : v1;
    }

    u16* pw = &Ps[w][0];
#pragma unroll
    for (int i = 0; i < 4; i++) {
      float mx = fmaxf(pv0[i], pv1[i]);
      mx = fmaxf(mx, __shfl_xor(mx, 1));
      mx = fmaxf(mx, __shfl_xor(mx, 2));
      mx = fmaxf(mx, __shfl_xor(mx, 4));
      mx = fmaxf(mx, __shfl_xor(mx, 8));
      float mn = fmaxf(m_i[i], mx);
      float f = __expf(m_i[i] - mn);
      float p0 = __expf(pv0[i] - mn);
      float p1 = __expf(pv1[i] - mn);
      float rs = p0 + p1;
      rs += __shfl_xor(rs, 1);
      rs += __shfl_xor(rs, 2);
      rs += __shfl_xor(rs, 4);
      rs += __shfl_xor(rs, 8);
      l_i[i] = l_i[i] * f + rs;
      m_i[i] = mn;
#pragma unroll
      for (int nf = 0; nf < 8; nf++) o[nf][i] *= f;
      pw[(4 * lg + i) * 32 + lr] = f2bf(p0);
      pw[(4 * lg + i) * 32 + 16 + lr] = f2bf(p1);
    }

    // cross-lane P via LDS (same wave): drain LDS writes, block reordering
    asm volatile("s_waitcnt lgkmcnt(0)" ::: "memory");
    bfx8 pa = *(const bfx8*)(pw + lr * 32 + lg * 8);
#pragma unroll
    for (int nf = 0; nf < 8; nf++) {
      int vrow = nf * 16 + lr;
      int cs = lg ^ (vrow & 3);
      bfx8 vf = *(const bfx8*)(Vs + vrow * 32 + cs * 8);
      o[nf] = __builtin_amdgcn_mfma_f32_16x16x32_bf16(pa, vf, o[nf], 0, 0, 0);
    }
    __syncthreads();
  }

  float inv[4];
#pragma unroll
  for (int i = 0; i < 4; i++) inv[i] = 1.0f / l_i[i];
  u16* ob = Og + ((size_t)(b * T_ + qr0)) * DM + h * HD;
#pragma unroll
  for (int nf = 0; nf < 8; nf++)
#pragma unroll
    for (int i = 0; i < 4; i++)
      ob[(size_t)(4 * lg + i) * DM + nf * 16 + lr] = f2bf(o[nf][i] * inv[i]);
}

// ---------------- launch ----------------
extern "C" void kernel_launch(void* const* d_in, const int* in_sizes, int n_in,
                              void* d_out, int out_size, void* d_ws, size_t ws_size,
                              hipStream_t stream) {
  const float* x = (const float*)d_in[0];
  // d_in[1] = mask (unused; causal recomputed)
  const float* cosp = (const float*)d_in[2];
  const float* sinp = (const float*)d_in[3];
  const float* Wq = (const float*)d_in[4];
  const float* Wk = (const float*)d_in[5];
  const float* Wv = (const float*)d_in[6];
  const float* Wo = (const float*)d_in[7];
  const float* bo = (const float*)d_in[8];
  const float* gq = (const float*)d_in[9];
  const float* gk = (const float*)d_in[10];

  char* ws = (char*)d_ws;
  u16* xbf  = (u16*)(ws + 0);           // 16 MB
  u16* wqkv = (u16*)(ws + 16777216);    // 16 MB (Wq|Wk|Wv rows stacked)
  u16* wo   = (u16*)(ws + 33554432);    // 8 MB
  u16* qkv  = (u16*)(ws + 41943040);    // 32 MB bf16 [4096][4096]
  u16* qb   = (u16*)(ws + 75497472);    // 16 MB [b][h][t][d]
  u16* kb   = (u16*)(ws + 92274688);    // 8 MB  [b][hkv][t][d] swizzled
  u16* vt   = (u16*)(ws + 100663296);   // 8 MB  [b][hkv][d][t] swizzled
  u16* ab   = (u16*)(ws + 109051904);   // 16 MB [b][t][h*d]
  float* out = (float*)d_out;

  k_cvt<<<8192, 256, 0, stream>>>(x, xbf, 8388608);
  k_cvt<<<4096, 256, 0, stream>>>(Wq, wqkv, 4194304);
  k_cvt<<<2048, 256, 0, stream>>>(Wk, wqkv + 4194304, 2097152);
  k_cvt<<<2048, 256, 0, stream>>>(Wv, wqkv + 6291456, 2097152);
  k_cvt<<<4096, 256, 0, stream>>>(Wo, wo, 4194304);

  k_gemm<false><<<1024, 256, 0, stream>>>(xbf, wqkv, qkv, nullptr, 4096, 4096, 2048);
  k_qkpost<<<1536, 256, 0, stream>>>(qkv, cosp, sinp, gq, gk, qb, kb);
  k_vtr<<<512, 256, 0, stream>>>(qkv, vt);
  k_attn<<<1024, 256, 0, stream>>>(qb, kb, vt, ab);
  k_gemm<true><<<512, 256, 0, stream>>>(ab, wo, out, bo, 4096, 2048, 2048);
}

// Round 2
// 274.589 us; speedup vs baseline: 1.4244x; 1.4244x over previous
//
#include <hip/hip_runtime.h>
#include <stdint.h>

#define B_ 2
#define T_ 2048
#define DM 2048
#define NH 16
#define NKV 8
#define HD 128
#define NQKV 4096
#define SCALE_ 0.08838834764831845f  // 1/sqrt(128)
#define SC2_ 0.12753102765f          // SCALE * log2(e)

typedef float fx4 __attribute__((ext_vector_type(4)));
typedef __bf16 bfx8 __attribute__((ext_vector_type(8)));
typedef unsigned short u16;
typedef unsigned int u32;

typedef __attribute__((address_space(1))) const void gas_t;
typedef __attribute__((address_space(3))) void las_t;

__device__ __forceinline__ u16 f2bf(float f) {
  u32 u = __float_as_uint(f);
  u = (u + 0x7fffu + ((u >> 16) & 1u)) >> 16;
  return (u16)u;
}

// async global->LDS, 16B per lane; lds arg must be wave-uniform base + lane*16
__device__ __forceinline__ void stage16(const void* g, void* l) {
  __builtin_amdgcn_global_load_lds((gas_t*)(uintptr_t)g, (las_t*)(uintptr_t)l,
                                   16, 0, 0);
}

// ---------------- fp32 -> bf16 convert ----------------
__global__ void k_cvt(const float* __restrict__ in, u16* __restrict__ out, int n) {
  int i = (blockIdx.x * blockDim.x + threadIdx.x) * 4;
  if (i + 3 < n) {
    float4 v = *(const float4*)(in + i);
    u32 w0 = (u32)f2bf(v.x) | ((u32)f2bf(v.y) << 16);
    u32 w1 = (u32)f2bf(v.z) | ((u32)f2bf(v.w) << 16);
    *(uint2*)(out + i) = make_uint2(w0, w1);
  }
}

// ---------------- bf16 GEMM: C[M][N] = A[M][K] * B[N][K]^T ----------------
template <bool OUT_F32>
__global__ __launch_bounds__(256, 2) void k_gemm(const u16* __restrict__ A,
                                                 const u16* __restrict__ Bm,
                                                 void* __restrict__ Cv,
                                                 const float* __restrict__ bias,
                                                 int M, int N, int K) {
  __shared__ __align__(16) u16 As[128 * 32];
  __shared__ __align__(16) u16 Bs[128 * 32];
  const int nbn = N >> 7;
  const int bm = blockIdx.x / nbn, bn = blockIdx.x % nbn;
  const int tid = threadIdx.x;
  const int w = tid >> 6, lane = tid & 63;
  const int wr = w >> 1, wc = w & 1;
  const int lr = lane & 15, lg = lane >> 4;
  const u16* Ab = A + (size_t)bm * 128 * K;
  const u16* Bb = Bm + (size_t)bn * 128 * K;
  const int srow = lane >> 2, skc = (lane & 3) * 8;

  fx4 zero4 = {0.f, 0.f, 0.f, 0.f};
  fx4 acc[4][4];
#pragma unroll
  for (int m = 0; m < 4; m++)
#pragma unroll
    for (int n = 0; n < 4; n++) acc[m][n] = zero4;

  for (int k0 = 0; k0 < K; k0 += 32) {
#pragma unroll
    for (int t = 0; t < 2; t++) {
      int s = w + t * 4;
      stage16(Ab + (size_t)(s * 16 + srow) * K + k0 + skc, As + s * 512 + lane * 8);
      stage16(Bb + (size_t)(s * 16 + srow) * K + k0 + skc, Bs + s * 512 + lane * 8);
    }
    __syncthreads();
    bfx8 af[4], bfr[4];
#pragma unroll
    for (int m = 0; m < 4; m++)
      af[m] = *(const bfx8*)(As + (wr * 64 + m * 16 + lr) * 32 + lg * 8);
#pragma unroll
    for (int n = 0; n < 4; n++)
      bfr[n] = *(const bfx8*)(Bs + (wc * 64 + n * 16 + lr) * 32 + lg * 8);
#pragma unroll
    for (int m = 0; m < 4; m++)
#pragma unroll
      for (int n = 0; n < 4; n++)
        acc[m][n] = __builtin_amdgcn_mfma_f32_16x16x32_bf16(af[m], bfr[n], acc[m][n], 0, 0, 0);
    __syncthreads();
  }

  const int r0 = bm * 128 + wr * 64, c0 = bn * 128 + wc * 64;
#pragma unroll
  for (int m = 0; m < 4; m++) {
#pragma unroll
    for (int n = 0; n < 4; n++) {
      int c = c0 + n * 16 + lr;
#pragma unroll
      for (int i = 0; i < 4; i++) {
        int r = r0 + m * 16 + lg * 4 + i;
        if (OUT_F32) {
          ((float*)Cv)[(size_t)r * N + c] = acc[m][n][i] + bias[c];
        } else {
          ((u16*)Cv)[(size_t)r * N + c] = f2bf(acc[m][n][i]);
        }
      }
    }
  }
}

// ---------------- Q/K epilogue: rmsnorm + rope, relayout ----------------
__global__ __launch_bounds__(256) void k_qkpost(const u16* __restrict__ qkv,
                                                const float* __restrict__ cosp,
                                                const float* __restrict__ sinp,
                                                const float* __restrict__ gq,
                                                const float* __restrict__ gk,
                                                u16* __restrict__ Qo,
                                                u16* __restrict__ Ko) {
  int bi = blockIdx.x;
  int hh = bi % 24;
  int t64 = (bi / 24) % 32;
  int b = bi / 768;
  int tid = threadIdx.x;
  int j = tid >> 2, p = tid & 3;
  int t = t64 * 64 + j;
  bool isq = hh < 16;
  int colbase = isq ? hh * 128 : 2048 + (hh - 16) * 128;
  const u16* src = qkv + ((size_t)(b * T_ + t)) * NQKV + colbase + p * 32;

  float xv[32];
#pragma unroll
  for (int c = 0; c < 4; c++) {
    uint4 raw = *(const uint4*)(src + c * 8);
    u32 wd[4] = {raw.x, raw.y, raw.z, raw.w};
#pragma unroll
    for (int q2 = 0; q2 < 4; q2++) {
      xv[c * 8 + q2 * 2 + 0] = __uint_as_float(wd[q2] << 16);
      xv[c * 8 + q2 * 2 + 1] = __uint_as_float(wd[q2] & 0xffff0000u);
    }
  }
  float ss = 0.f;
#pragma unroll
  for (int i = 0; i < 32; i++) ss += xv[i] * xv[i];
  ss += __shfl_xor(ss, 1);
  ss += __shfl_xor(ss, 2);
  float rinv = rsqrtf(ss * (1.0f / 128.0f) + 1e-6f);
  const float* g = isq ? gq : gk;
  const float* cr = cosp + (size_t)t * 128 + p * 32;
  const float* sr = sinp + (size_t)t * 128 + p * 32;

  float ov[32];
#pragma unroll
  for (int i = 0; i < 32; i++) {
    float y = xv[i] * rinv * g[p * 32 + i];
    float oth = __shfl_xor(y, 2);
    float rot = (p < 2) ? -oth : oth;
    ov[i] = y * cr[i] + rot * sr[i];
  }

  uint4 pk[4];
#pragma unroll
  for (int c = 0; c < 4; c++) {
    u32 wd[4];
#pragma unroll
    for (int q2 = 0; q2 < 4; q2++)
      wd[q2] = (u32)f2bf(ov[c * 8 + q2 * 2]) | ((u32)f2bf(ov[c * 8 + q2 * 2 + 1]) << 16);
    pk[c] = make_uint4(wd[0], wd[1], wd[2], wd[3]);
  }

  if (isq) {
    u16* dst = Qo + (((size_t)(b * NH + hh)) * T_ + t) * HD + p * 32;
#pragma unroll
    for (int c = 0; c < 4; c++) *(uint4*)(dst + c * 8) = pk[c];
  } else {
    int hk = hh - 16;
    u16* dstrow = Ko + (((size_t)(b * NKV + hk)) * T_ + t) * HD;
#pragma unroll
    for (int c = 0; c < 4; c++) {
      int C = p * 4 + c;
      int Cs = C ^ (t & 7);  // XOR swizzle (16 chunks/row), matches attn read
      *(uint4*)(dstrow + Cs * 8) = pk[c];
    }
  }
}

// ---------------- V transpose: qkv[...,3072+] -> vt[b][hkv][d][t] ----------------
// 8-chunk swizzle within each aligned 64-token group: chunk' = chunk ^ (d&7)
__global__ __launch_bounds__(256) void k_vtr(const u16* __restrict__ qkv,
                                             u16* __restrict__ vt) {
  __shared__ __align__(16) u16 sm[128 * 64];
  int bi = blockIdx.x;
  int hv = bi & 7;
  int t64 = (bi >> 3) & 31;
  int b = bi >> 8;
  int tid = threadIdx.x;
#pragma unroll
  for (int it = 0; it < 4; it++) {
    int idx = tid + it * 256;
    int tok = idx >> 4, c = idx & 15;
    uint4 raw = *(const uint4*)(qkv + ((size_t)(b * T_ + t64 * 64 + tok)) * NQKV +
                                3072 + hv * 128 + c * 8);
    u32 wd[4] = {raw.x, raw.y, raw.z, raw.w};
#pragma unroll
    for (int q2 = 0; q2 < 4; q2++) {
      sm[(c * 8 + q2 * 2 + 0) * 64 + tok] = (u16)(wd[q2] & 0xffffu);
      sm[(c * 8 + q2 * 2 + 1) * 64 + tok] = (u16)(wd[q2] >> 16);
    }
  }
  __syncthreads();
  int d = tid >> 1, half = tid & 1;
  size_t rowb = (((size_t)(b * NKV + hv)) * HD + d) * T_ + t64 * 64;
#pragma unroll
  for (int c = 0; c < 4; c++) {
    int cg = half * 4 + c;            // chunk within the 64-token group
    int cs = cg ^ (d & 7);            // 8-chunk XOR swizzle
    u32 wd[4];
#pragma unroll
    for (int q2 = 0; q2 < 4; q2++) {
      u32 lo = sm[d * 64 + half * 32 + c * 8 + 2 * q2];
      u32 hi = sm[d * 64 + half * 32 + c * 8 + 2 * q2 + 1];
      wd[q2] = lo | (hi << 16);
    }
    *(uint4*)(vt + rowb + cs * 8) = make_uint4(wd[0], wd[1], wd[2], wd[3]);
  }
}

// ---------------- flash attention (causal, GQA rep=2) ----------------
// grid = B*NH*16; block handles q-tiles z and 31-z sequentially (33 chunk
// passes of KV=64 each -> perfectly balanced). 4 waves x 16 q-rows.
// Double-buffered K/V LDS, 1 barrier/chunk, defer-rescale softmax.
__global__ __launch_bounds__(256, 2) void k_attn(const u16* __restrict__ Qg,
                                                 const u16* __restrict__ Kg,
                                                 const u16* __restrict__ Vg,
                                                 u16* __restrict__ Og) {
  __shared__ __align__(16) u16 Ks[2][64 * 128];
  __shared__ __align__(16) u16 Vs[2][128 * 64];
  __shared__ __align__(16) u16 Ps[4][16 * 64];
  const int bi = blockIdx.x;
  const int z = bi & 15, h = (bi >> 4) & 15, b = bi >> 8;
  const int hkv = h >> 1;
  const int tid = threadIdx.x, w = tid >> 6, lane = tid & 63;
  const int lr = lane & 15, lg = lane >> 4;
  const u16* kb = Kg + ((size_t)(b * NKV + hkv)) * T_ * HD;
  const u16* vb = Vg + ((size_t)(b * NKV + hkv)) * HD * T_;
  u16* pw = &Ps[w][0];
  const fx4 zero4 = {0.f, 0.f, 0.f, 0.f};

  int cur = 0;
  auto stageKV = [&](int buf, int kv0) {
    u16* Kd = &Ks[buf][0];
    u16* Vd = &Vs[buf][0];
#pragma unroll
    for (int it = 0; it < 4; it++) {
      int r = it * 16 + (tid >> 4);
      stage16(kb + (size_t)(kv0 + r) * HD + (tid & 15) * 8, Kd + it * 2048 + tid * 8);
      int d = it * 32 + (tid >> 3);
      stage16(vb + (size_t)d * T_ + kv0 + (tid & 7) * 8, Vd + it * 2048 + tid * 8);
    }
  };

#pragma unroll 1
  for (int hf = 0; hf < 2; hf++) {
    const int zt = hf ? (31 - z) : z;
    const int qr0 = zt * 64 + w * 16;
    const u16* qbase = Qg + (((size_t)(b * NH + h)) * T_ + qr0 + lr) * HD;
    bfx8 qf[4];
#pragma unroll
    for (int kk = 0; kk < 4; kk++) qf[kk] = *(const bfx8*)(qbase + kk * 32 + lg * 8);

    fx4 o[8];
#pragma unroll
    for (int nf = 0; nf < 8; nf++) o[nf] = zero4;
    float m_i[4] = {-1e30f, -1e30f, -1e30f, -1e30f};
    float l_i[4] = {0.f, 0.f, 0.f, 0.f};
    const int nch = zt + 1;

    stageKV(cur, 0);
    __syncthreads();

#pragma unroll 1
    for (int ch = 0; ch < nch; ch++) {
      if (ch + 1 < nch) stageKV(cur ^ 1, (ch + 1) * 64);
      const u16* Kd = &Ks[cur][0];
      const u16* Vd = &Vs[cur][0];
      const int kv0 = ch * 64;

      // ---- S = Q K^T (16q x 64kv) ----
      fx4 sa[4];
#pragma unroll
      for (int n = 0; n < 4; n++) sa[n] = zero4;
      __builtin_amdgcn_s_setprio(1);
#pragma unroll
      for (int n = 0; n < 4; n++) {
        const int kvl = n * 16 + lr;
        const u16* krow = Kd + kvl * 128;
#pragma unroll
        for (int kk = 0; kk < 4; kk++) {
          int cs = (kk * 4 + lg) ^ (kvl & 7);
          bfx8 kf = *(const bfx8*)(krow + cs * 8);
          sa[n] = __builtin_amdgcn_mfma_f32_16x16x32_bf16(qf[kk], kf, sa[n], 0, 0, 0);
        }
      }
      __builtin_amdgcn_s_setprio(0);

      // ---- scale (+mask on diagonal chunk), log2 domain ----
      float pv[4][4];
      if (ch == zt) {
#pragma unroll
        for (int n = 0; n < 4; n++) {
          int kcol = kv0 + n * 16 + lr;
#pragma unroll
          for (int i = 0; i < 4; i++) {
            int r = qr0 + 4 * lg + i;
            pv[n][i] = (kcol > r) ? -1e30f : sa[n][i] * SC2_;
          }
        }
      } else {
#pragma unroll
        for (int n = 0; n < 4; n++)
#pragma unroll
          for (int i = 0; i < 4; i++) pv[n][i] = sa[n][i] * SC2_;
      }

      // ---- row max + defer-rescale ----
      float mx[4];
      bool need = false;
#pragma unroll
      for (int i = 0; i < 4; i++) {
        float m = fmaxf(fmaxf(pv[0][i], pv[1][i]), fmaxf(pv[2][i], pv[3][i]));
        m = fmaxf(m, __shfl_xor(m, 1));
        m = fmaxf(m, __shfl_xor(m, 2));
        m = fmaxf(m, __shfl_xor(m, 4));
        m = fmaxf(m, __shfl_xor(m, 8));
        mx[i] = m;
        need = need || (m > m_i[i] + 8.0f);
      }
      if (__any(need)) {
#pragma unroll
        for (int i = 0; i < 4; i++) {
          float mn = fmaxf(m_i[i], mx[i]);
          float f = exp2f(m_i[i] - mn);
          m_i[i] = mn;
          l_i[i] *= f;
#pragma unroll
          for (int nf = 0; nf < 8; nf++) o[nf][i] *= f;
        }
      }

      // ---- P = exp2(pv - m), per-lane partial l, store swizzled bf16 ----
#pragma unroll
      for (int i = 0; i < 4; i++) {
        int q = 4 * lg + i;
        u16* prow = pw + q * 64;
#pragma unroll
        for (int n = 0; n < 4; n++) {
          float p = exp2f(pv[n][i] - m_i[i]);
          l_i[i] += p;
          int chn = ((n * 2 + (lr >> 3)) ^ (q & 7));
          prow[chn * 8 + (lr & 7)] = f2bf(p);
        }
      }
      asm volatile("s_waitcnt lgkmcnt(0)" ::: "memory");

      // ---- O += P V ----
      bfx8 pa[2];
#pragma unroll
      for (int ks = 0; ks < 2; ks++) {
        int cp = (4 * ks + lg) ^ (lr & 7);
        pa[ks] = *(const bfx8*)(pw + lr * 64 + cp * 8);
      }
      __builtin_amdgcn_s_setprio(1);
#pragma unroll
      for (int nf = 0; nf < 8; nf++) {
        int d = nf * 16 + lr;
        const u16* vrow = Vd + d * 64;
#pragma unroll
        for (int ks = 0; ks < 2; ks++) {
          int cv = (4 * ks + lg) ^ (d & 7);
          bfx8 vf = *(const bfx8*)(vrow + cv * 8);
          o[nf] = __builtin_amdgcn_mfma_f32_16x16x32_bf16(pa[ks], vf, o[nf], 0, 0, 0);
        }
      }
      __builtin_amdgcn_s_setprio(0);
      __syncthreads();
      cur ^= 1;
    }

    // ---- finalize: reduce per-lane l over the 16-lane row group ----
    float inv[4];
#pragma unroll
    for (int i = 0; i < 4; i++) {
      float l = l_i[i];
      l += __shfl_xor(l, 1);
      l += __shfl_xor(l, 2);
      l += __shfl_xor(l, 4);
      l += __shfl_xor(l, 8);
      inv[i] = 1.0f / l;
    }
    u16* ob = Og + ((size_t)(b * T_ + qr0)) * DM + h * HD;
#pragma unroll
    for (int nf = 0; nf < 8; nf++)
#pragma unroll
      for (int i = 0; i < 4; i++)
        ob[(size_t)(4 * lg + i) * DM + nf * 16 + lr] = f2bf(o[nf][i] * inv[i]);
  }
}

// ---------------- launch ----------------
extern "C" void kernel_launch(void* const* d_in, const int* in_sizes, int n_in,
                              void* d_out, int out_size, void* d_ws, size_t ws_size,
                              hipStream_t stream) {
  const float* x = (const float*)d_in[0];
  const float* cosp = (const float*)d_in[2];
  const float* sinp = (const float*)d_in[3];
  const float* Wq = (const float*)d_in[4];
  const float* Wk = (const float*)d_in[5];
  const float* Wv = (const float*)d_in[6];
  const float* Wo = (const float*)d_in[7];
  const float* bo = (const float*)d_in[8];
  const float* gq = (const float*)d_in[9];
  const float* gk = (const float*)d_in[10];

  char* ws = (char*)d_ws;
  u16* xbf  = (u16*)(ws + 0);           // 16 MB
  u16* wqkv = (u16*)(ws + 16777216);    // 16 MB
  u16* wo   = (u16*)(ws + 33554432);    // 8 MB
  u16* qkv  = (u16*)(ws + 41943040);    // 32 MB
  u16* qb   = (u16*)(ws + 75497472);    // 16 MB
  u16* kb   = (u16*)(ws + 92274688);    // 8 MB
  u16* vt   = (u16*)(ws + 100663296);   // 8 MB
  u16* ab   = (u16*)(ws + 109051904);   // 16 MB
  float* out = (float*)d_out;

  k_cvt<<<8192, 256, 0, stream>>>(x, xbf, 8388608);
  k_cvt<<<4096, 256, 0, stream>>>(Wq, wqkv, 4194304);
  k_cvt<<<2048, 256, 0, stream>>>(Wk, wqkv + 4194304, 2097152);
  k_cvt<<<2048, 256, 0, stream>>>(Wv, wqkv + 6291456, 2097152);
  k_cvt<<<4096, 256, 0, stream>>>(Wo, wo, 4194304);

  k_gemm<false><<<1024, 256, 0, stream>>>(xbf, wqkv, qkv, nullptr, 4096, 4096, 2048);
  k_qkpost<<<1536, 256, 0, stream>>>(qkv, cosp, sinp, gq, gk, qb, kb);
  k_vtr<<<512, 256, 0, stream>>>(qkv, vt);
  k_attn<<<512, 256, 0, stream>>>(qb, kb, vt, ab);
  k_gemm<true><<<512, 256, 0, stream>>>(ab, wo, out, bo, 4096, 2048, 2048);
}

// Round 3
// 262.019 us; speedup vs baseline: 1.4927x; 1.0480x over previous
//
#include <hip/hip_runtime.h>
#include <stdint.h>

#define B_ 2
#define T_ 2048
#define DM 2048
#define NH 16
#define NKV 8
#define HD 128
#define NQKV 4096
#define SCALE_ 0.08838834764831845f  // 1/sqrt(128)
#define SC2_ 0.12753102765f          // SCALE * log2(e)

typedef float fx4 __attribute__((ext_vector_type(4)));
typedef __bf16 bfx8 __attribute__((ext_vector_type(8)));
typedef unsigned short u16;
typedef unsigned int u32;

typedef __attribute__((address_space(1))) const void gas_t;
typedef __attribute__((address_space(3))) void las_t;

__device__ __forceinline__ u16 f2bf(float f) {
  u32 u = __float_as_uint(f);
  u = (u + 0x7fffu + ((u >> 16) & 1u)) >> 16;
  return (u16)u;
}

// async global->LDS, 16B per lane; lds arg must be wave-uniform base + lane*16
__device__ __forceinline__ void stage16(const void* g, void* l) {
  __builtin_amdgcn_global_load_lds((gas_t*)(uintptr_t)g, (las_t*)(uintptr_t)l,
                                   16, 0, 0);
}

// ---------------- fp32 -> bf16 convert ----------------
__global__ void k_cvt(const float* __restrict__ in, u16* __restrict__ out, int n) {
  int i = (blockIdx.x * blockDim.x + threadIdx.x) * 4;
  if (i + 3 < n) {
    float4 v = *(const float4*)(in + i);
    u32 w0 = (u32)f2bf(v.x) | ((u32)f2bf(v.y) << 16);
    u32 w1 = (u32)f2bf(v.z) | ((u32)f2bf(v.w) << 16);
    *(uint2*)(out + i) = make_uint2(w0, w1);
  }
}

// ======== 256x256 8-phase GEMM (T2+T3+T4+T5): C[M][N] = A[M][K] B[N][K]^T ========
// 512 thr = 8 waves (2M x 4N), per-wave out 128x64. BK=64 as 2 K-halves of 32.
// LDS: per matrix [2 tile-buf][2 khalf][256 rows][32 cols] bf16 = 64KB; total 128KB.
// Phase j of tile t: j0:{rd A-lo/B kh0, stage A-kh1(t+1)} j1:{rd A-hi kh0, stage B-kh1(t+1)}
// j2:{rd A-lo/B kh1, stage A-kh0(t+2)} j3:{rd A-hi kh1, stage B-kh0(t+2), vmcnt(4)}
// Each phase: reads/stage -> barrier -> lgkmcnt(0)+sched_barrier -> 16 MFMA -> barrier.
__global__ __launch_bounds__(512, 2) void k_gemm256(const u16* __restrict__ A,
                                                    const u16* __restrict__ Bm,
                                                    u16* __restrict__ C,
                                                    int M, int N, int K) {
  __shared__ __align__(16) u16 As[2][2][256 * 32];
  __shared__ __align__(16) u16 Bs[2][2][256 * 32];
  const int nbn = N >> 8;
  const int bm = blockIdx.x / nbn, bn = blockIdx.x % nbn;
  const int tid = threadIdx.x;
  const int w = tid >> 6, lane = tid & 63;
  const int wm = w >> 2, wn = w & 3;
  const int lr = lane & 15, lg = lane >> 4;
  const int cw = (lg ^ ((lr >> 1) & 3)) * 8;  // swizzled chunk offset (elems)
  const u16* Ab = A + (size_t)bm * 256 * K;
  const u16* Bb = Bm + (size_t)bn * 256 * K;
  const int NT = K >> 6;

  // stage one K-half region (256 rows x 32 cols): 2 x 16B per thread.
  // global source chunk pre-swizzled; LDS dest linear (rule 21).
  auto stage = [&](const u16* gb, u16* region, int tile, int kh) {
#pragma unroll
    for (int i = 0; i < 2; i++) {
      int q = tid + i * 512;
      int row = q >> 2, ch = q & 3;
      int sc = ch ^ ((row >> 1) & 3);
      stage16(gb + (size_t)row * K + tile * 64 + kh * 32 + sc * 8, region + q * 8);
    }
  };

  fx4 acc[8][4];
  const fx4 zero4 = {0.f, 0.f, 0.f, 0.f};
#pragma unroll
  for (int m = 0; m < 8; m++)
#pragma unroll
    for (int n = 0; n < 4; n++) acc[m][n] = zero4;

  // prologue: tile0 (all 4 halves) + tile1 kh0 halves; wait tile0 landed.
  stage(Ab, &As[0][0][0], 0, 0);
  stage(Bb, &Bs[0][0][0], 0, 0);
  stage(Ab, &As[0][1][0], 0, 1);
  stage(Bb, &Bs[0][1][0], 0, 1);
  stage(Ab, &As[1][0][0], 1, 0);
  stage(Bb, &Bs[1][0][0], 1, 0);
  asm volatile("s_waitcnt vmcnt(4)" ::: "memory");
  __builtin_amdgcn_s_barrier();

  const int arow = (wm * 128 + lr) * 32;  // elem offset of A row base in region
  const int brow = (wn * 64 + lr) * 32;
  bfx8 af[4], bf[4];

#pragma unroll 1
  for (int t = 0; t < NT; t++) {
    const u16* A0 = &As[t & 1][0][0];
    const u16* A1 = &As[t & 1][1][0];
    const u16* B0 = &Bs[t & 1][0][0];
    const u16* B1 = &Bs[t & 1][1][0];
    const int p1 = (t + 1) & 1, p2 = t & 1;

    // ---------- phase 0: kk0, m-half 0 ----------
#pragma unroll
    for (int mi = 0; mi < 4; mi++) af[mi] = *(const bfx8*)(A0 + arow + mi * 512 + cw);
#pragma unroll
    for (int n = 0; n < 4; n++) bf[n] = *(const bfx8*)(B0 + brow + n * 512 + cw);
    if (t + 1 < NT) stage(Ab, &As[p1][1][0], t + 1, 1);
    __builtin_amdgcn_s_barrier();
    asm volatile("s_waitcnt lgkmcnt(0)" ::: "memory");
    __builtin_amdgcn_sched_barrier(0);
    __builtin_amdgcn_s_setprio(1);
#pragma unroll
    for (int mi = 0; mi < 4; mi++)
#pragma unroll
      for (int n = 0; n < 4; n++)
        acc[mi][n] = __builtin_amdgcn_mfma_f32_16x16x32_bf16(af[mi], bf[n], acc[mi][n], 0, 0, 0);
    __builtin_amdgcn_s_setprio(0);
    __builtin_amdgcn_s_barrier();

    // ---------- phase 1: kk0, m-half 1 (B frags held) ----------
#pragma unroll
    for (int mi = 0; mi < 4; mi++)
      af[mi] = *(const bfx8*)(A0 + arow + 2048 + mi * 512 + cw);
    if (t + 1 < NT) stage(Bb, &Bs[p1][1][0], t + 1, 1);
    __builtin_amdgcn_s_barrier();
    asm volatile("s_waitcnt lgkmcnt(0)" ::: "memory");
    __builtin_amdgcn_sched_barrier(0);
    __builtin_amdgcn_s_setprio(1);
#pragma unroll
    for (int mi = 0; mi < 4; mi++)
#pragma unroll
      for (int n = 0; n < 4; n++)
        acc[4 + mi][n] = __builtin_amdgcn_mfma_f32_16x16x32_bf16(af[mi], bf[n], acc[4 + mi][n], 0, 0, 0);
    __builtin_amdgcn_s_setprio(0);
    __builtin_amdgcn_s_barrier();

    // ---------- phase 2: kk1, m-half 0 ----------
#pragma unroll
    for (int mi = 0; mi < 4; mi++) af[mi] = *(const bfx8*)(A1 + arow + mi * 512 + cw);
#pragma unroll
    for (int n = 0; n < 4; n++) bf[n] = *(const bfx8*)(B1 + brow + n * 512 + cw);
    if (t + 2 < NT) stage(Ab, &As[p2][0][0], t + 2, 0);
    __builtin_amdgcn_s_barrier();
    asm volatile("s_waitcnt lgkmcnt(0)" ::: "memory");
    __builtin_amdgcn_sched_barrier(0);
    __builtin_amdgcn_s_setprio(1);
#pragma unroll
    for (int mi = 0; mi < 4; mi++)
#pragma unroll
      for (int n = 0; n < 4; n++)
        acc[mi][n] = __builtin_amdgcn_mfma_f32_16x16x32_bf16(af[mi], bf[n], acc[mi][n], 0, 0, 0);
    __builtin_amdgcn_s_setprio(0);
    __builtin_amdgcn_s_barrier();

    // ---------- phase 3: kk1, m-half 1 ----------
#pragma unroll
    for (int mi = 0; mi < 4; mi++)
      af[mi] = *(const bfx8*)(A1 + arow + 2048 + mi * 512 + cw);
    if (t + 2 < NT) stage(Bb, &Bs[p2][0][0], t + 2, 0);
    __builtin_amdgcn_s_barrier();
    asm volatile("s_waitcnt lgkmcnt(0)" ::: "memory");
    __builtin_amdgcn_sched_barrier(0);
    __builtin_amdgcn_s_setprio(1);
#pragma unroll
    for (int mi = 0; mi < 4; mi++)
#pragma unroll
      for (int n = 0; n < 4; n++)
        acc[4 + mi][n] = __builtin_amdgcn_mfma_f32_16x16x32_bf16(af[mi], bf[n], acc[4 + mi][n], 0, 0, 0);
    __builtin_amdgcn_s_setprio(0);
    asm volatile("s_waitcnt vmcnt(4)" ::: "memory");  // next tile fully landed
    __builtin_amdgcn_s_barrier();
  }

  const int r0 = bm * 256 + wm * 128, c0 = bn * 256 + wn * 64;
#pragma unroll
  for (int m = 0; m < 8; m++) {
#pragma unroll
    for (int n = 0; n < 4; n++) {
      int c = c0 + n * 16 + lr;
#pragma unroll
      for (int i = 0; i < 4; i++)
        C[(size_t)(r0 + m * 16 + lg * 4 + i) * N + c] = f2bf(acc[m][n][i]);
    }
  }
}

// ---------------- bf16 GEMM (128^2 m97-structure), used for out-proj ----------------
template <bool OUT_F32>
__global__ __launch_bounds__(256, 2) void k_gemm(const u16* __restrict__ A,
                                                 const u16* __restrict__ Bm,
                                                 void* __restrict__ Cv,
                                                 const float* __restrict__ bias,
                                                 int M, int N, int K) {
  __shared__ __align__(16) u16 As[128 * 32];
  __shared__ __align__(16) u16 Bs[128 * 32];
  const int nbn = N >> 7;
  const int bm = blockIdx.x / nbn, bn = blockIdx.x % nbn;
  const int tid = threadIdx.x;
  const int w = tid >> 6, lane = tid & 63;
  const int wr = w >> 1, wc = w & 1;
  const int lr = lane & 15, lg = lane >> 4;
  const u16* Ab = A + (size_t)bm * 128 * K;
  const u16* Bb = Bm + (size_t)bn * 128 * K;
  const int srow = lane >> 2, skc = (lane & 3) * 8;

  fx4 zero4 = {0.f, 0.f, 0.f, 0.f};
  fx4 acc[4][4];
#pragma unroll
  for (int m = 0; m < 4; m++)
#pragma unroll
    for (int n = 0; n < 4; n++) acc[m][n] = zero4;

  for (int k0 = 0; k0 < K; k0 += 32) {
#pragma unroll
    for (int t = 0; t < 2; t++) {
      int s = w + t * 4;
      stage16(Ab + (size_t)(s * 16 + srow) * K + k0 + skc, As + s * 512 + lane * 8);
      stage16(Bb + (size_t)(s * 16 + srow) * K + k0 + skc, Bs + s * 512 + lane * 8);
    }
    __syncthreads();
    bfx8 af[4], bfr[4];
#pragma unroll
    for (int m = 0; m < 4; m++)
      af[m] = *(const bfx8*)(As + (wr * 64 + m * 16 + lr) * 32 + lg * 8);
#pragma unroll
    for (int n = 0; n < 4; n++)
      bfr[n] = *(const bfx8*)(Bs + (wc * 64 + n * 16 + lr) * 32 + lg * 8);
#pragma unroll
    for (int m = 0; m < 4; m++)
#pragma unroll
      for (int n = 0; n < 4; n++)
        acc[m][n] = __builtin_amdgcn_mfma_f32_16x16x32_bf16(af[m], bfr[n], acc[m][n], 0, 0, 0);
    __syncthreads();
  }

  const int r0 = bm * 128 + wr * 64, c0 = bn * 128 + wc * 64;
#pragma unroll
  for (int m = 0; m < 4; m++) {
#pragma unroll
    for (int n = 0; n < 4; n++) {
      int c = c0 + n * 16 + lr;
#pragma unroll
      for (int i = 0; i < 4; i++) {
        int r = r0 + m * 16 + lg * 4 + i;
        if (OUT_F32) {
          ((float*)Cv)[(size_t)r * N + c] = acc[m][n][i] + bias[c];
        } else {
          ((u16*)Cv)[(size_t)r * N + c] = f2bf(acc[m][n][i]);
        }
      }
    }
  }
}

// ---------------- Q/K epilogue: rmsnorm + rope, relayout ----------------
__global__ __launch_bounds__(256) void k_qkpost(const u16* __restrict__ qkv,
                                                const float* __restrict__ cosp,
                                                const float* __restrict__ sinp,
                                                const float* __restrict__ gq,
                                                const float* __restrict__ gk,
                                                u16* __restrict__ Qo,
                                                u16* __restrict__ Ko) {
  int bi = blockIdx.x;
  int hh = bi % 24;
  int t64 = (bi / 24) % 32;
  int b = bi / 768;
  int tid = threadIdx.x;
  int j = tid >> 2, p = tid & 3;
  int t = t64 * 64 + j;
  bool isq = hh < 16;
  int colbase = isq ? hh * 128 : 2048 + (hh - 16) * 128;
  const u16* src = qkv + ((size_t)(b * T_ + t)) * NQKV + colbase + p * 32;

  float xv[32];
#pragma unroll
  for (int c = 0; c < 4; c++) {
    uint4 raw = *(const uint4*)(src + c * 8);
    u32 wd[4] = {raw.x, raw.y, raw.z, raw.w};
#pragma unroll
    for (int q2 = 0; q2 < 4; q2++) {
      xv[c * 8 + q2 * 2 + 0] = __uint_as_float(wd[q2] << 16);
      xv[c * 8 + q2 * 2 + 1] = __uint_as_float(wd[q2] & 0xffff0000u);
    }
  }
  float ss = 0.f;
#pragma unroll
  for (int i = 0; i < 32; i++) ss += xv[i] * xv[i];
  ss += __shfl_xor(ss, 1);
  ss += __shfl_xor(ss, 2);
  float rinv = rsqrtf(ss * (1.0f / 128.0f) + 1e-6f);
  const float* g = isq ? gq : gk;
  const float* cr = cosp + (size_t)t * 128 + p * 32;
  const float* sr = sinp + (size_t)t * 128 + p * 32;

  float ov[32];
#pragma unroll
  for (int i = 0; i < 32; i++) {
    float y = xv[i] * rinv * g[p * 32 + i];
    float oth = __shfl_xor(y, 2);
    float rot = (p < 2) ? -oth : oth;
    ov[i] = y * cr[i] + rot * sr[i];
  }

  uint4 pk[4];
#pragma unroll
  for (int c = 0; c < 4; c++) {
    u32 wd[4];
#pragma unroll
    for (int q2 = 0; q2 < 4; q2++)
      wd[q2] = (u32)f2bf(ov[c * 8 + q2 * 2]) | ((u32)f2bf(ov[c * 8 + q2 * 2 + 1]) << 16);
    pk[c] = make_uint4(wd[0], wd[1], wd[2], wd[3]);
  }

  if (isq) {
    u16* dst = Qo + (((size_t)(b * NH + hh)) * T_ + t) * HD + p * 32;
#pragma unroll
    for (int c = 0; c < 4; c++) *(uint4*)(dst + c * 8) = pk[c];
  } else {
    int hk = hh - 16;
    u16* dstrow = Ko + (((size_t)(b * NKV + hk)) * T_ + t) * HD;
#pragma unroll
    for (int c = 0; c < 4; c++) {
      int C = p * 4 + c;
      int Cs = C ^ (t & 7);  // XOR swizzle (16 chunks/row), matches attn read
      *(uint4*)(dstrow + Cs * 8) = pk[c];
    }
  }
}

// ---------------- V transpose: qkv[...,3072+] -> vt[b][hkv][d][t] ----------------
__global__ __launch_bounds__(256) void k_vtr(const u16* __restrict__ qkv,
                                             u16* __restrict__ vt) {
  __shared__ __align__(16) u16 sm[128 * 64];
  int bi = blockIdx.x;
  int hv = bi & 7;
  int t64 = (bi >> 3) & 31;
  int b = bi >> 8;
  int tid = threadIdx.x;
#pragma unroll
  for (int it = 0; it < 4; it++) {
    int idx = tid + it * 256;
    int tok = idx >> 4, c = idx & 15;
    uint4 raw = *(const uint4*)(qkv + ((size_t)(b * T_ + t64 * 64 + tok)) * NQKV +
                                3072 + hv * 128 + c * 8);
    u32 wd[4] = {raw.x, raw.y, raw.z, raw.w};
#pragma unroll
    for (int q2 = 0; q2 < 4; q2++) {
      sm[(c * 8 + q2 * 2 + 0) * 64 + tok] = (u16)(wd[q2] & 0xffffu);
      sm[(c * 8 + q2 * 2 + 1) * 64 + tok] = (u16)(wd[q2] >> 16);
    }
  }
  __syncthreads();
  int d = tid >> 1, half = tid & 1;
  size_t rowb = (((size_t)(b * NKV + hv)) * HD + d) * T_ + t64 * 64;
#pragma unroll
  for (int c = 0; c < 4; c++) {
    int cg = half * 4 + c;
    int cs = cg ^ (d & 7);
    u32 wd[4];
#pragma unroll
    for (int q2 = 0; q2 < 4; q2++) {
      u32 lo = sm[d * 64 + half * 32 + c * 8 + 2 * q2];
      u32 hi = sm[d * 64 + half * 32 + c * 8 + 2 * q2 + 1];
      wd[q2] = lo | (hi << 16);
    }
    *(uint4*)(vt + rowb + cs * 8) = make_uint4(wd[0], wd[1], wd[2], wd[3]);
  }
}

// ---------------- flash attention (causal, GQA rep=2) ----------------
__global__ __launch_bounds__(256, 2) void k_attn(const u16* __restrict__ Qg,
                                                 const u16* __restrict__ Kg,
                                                 const u16* __restrict__ Vg,
                                                 u16* __restrict__ Og) {
  __shared__ __align__(16) u16 Ks[2][64 * 128];
  __shared__ __align__(16) u16 Vs[2][128 * 64];
  __shared__ __align__(16) u16 Ps[4][16 * 64];
  const int bi = blockIdx.x;
  const int z = bi & 15, h = (bi >> 4) & 15, b = bi >> 8;
  const int hkv = h >> 1;
  const int tid = threadIdx.x, w = tid >> 6, lane = tid & 63;
  const int lr = lane & 15, lg = lane >> 4;
  const u16* kb = Kg + ((size_t)(b * NKV + hkv)) * T_ * HD;
  const u16* vb = Vg + ((size_t)(b * NKV + hkv)) * HD * T_;
  u16* pw = &Ps[w][0];
  const fx4 zero4 = {0.f, 0.f, 0.f, 0.f};

  int cur = 0;
  auto stageKV = [&](int buf, int kv0) {
    u16* Kd = &Ks[buf][0];
    u16* Vd = &Vs[buf][0];
#pragma unroll
    for (int it = 0; it < 4; it++) {
      int r = it * 16 + (tid >> 4);
      stage16(kb + (size_t)(kv0 + r) * HD + (tid & 15) * 8, Kd + it * 2048 + tid * 8);
      int d = it * 32 + (tid >> 3);
      stage16(vb + (size_t)d * T_ + kv0 + (tid & 7) * 8, Vd + it * 2048 + tid * 8);
    }
  };

#pragma unroll 1
  for (int hf = 0; hf < 2; hf++) {
    const int zt = hf ? (31 - z) : z;
    const int qr0 = zt * 64 + w * 16;
    const u16* qbase = Qg + (((size_t)(b * NH + h)) * T_ + qr0 + lr) * HD;
    bfx8 qf[4];
#pragma unroll
    for (int kk = 0; kk < 4; kk++) qf[kk] = *(const bfx8*)(qbase + kk * 32 + lg * 8);

    fx4 o[8];
#pragma unroll
    for (int nf = 0; nf < 8; nf++) o[nf] = zero4;
    float m_i[4] = {-1e30f, -1e30f, -1e30f, -1e30f};
    float l_i[4] = {0.f, 0.f, 0.f, 0.f};
    const int nch = zt + 1;

    stageKV(cur, 0);
    __syncthreads();

#pragma unroll 1
    for (int ch = 0; ch < nch; ch++) {
      if (ch + 1 < nch) stageKV(cur ^ 1, (ch + 1) * 64);
      const u16* Kd = &Ks[cur][0];
      const u16* Vd = &Vs[cur][0];
      const int kv0 = ch * 64;

      fx4 sa[4];
#pragma unroll
      for (int n = 0; n < 4; n++) sa[n] = zero4;
      __builtin_amdgcn_s_setprio(1);
#pragma unroll
      for (int n = 0; n < 4; n++) {
        const int kvl = n * 16 + lr;
        const u16* krow = Kd + kvl * 128;
#pragma unroll
        for (int kk = 0; kk < 4; kk++) {
          int cs = (kk * 4 + lg) ^ (kvl & 7);
          bfx8 kf = *(const bfx8*)(krow + cs * 8);
          sa[n] = __builtin_amdgcn_mfma_f32_16x16x32_bf16(qf[kk], kf, sa[n], 0, 0, 0);
        }
      }
      __builtin_amdgcn_s_setprio(0);

      float pv[4][4];
      if (ch == zt) {
#pragma unroll
        for (int n = 0; n < 4; n++) {
          int kcol = kv0 + n * 16 + lr;
#pragma unroll
          for (int i = 0; i < 4; i++) {
            int r = qr0 + 4 * lg + i;
            pv[n][i] = (kcol > r) ? -1e30f : sa[n][i] * SC2_;
          }
        }
      } else {
#pragma unroll
        for (int n = 0; n < 4; n++)
#pragma unroll
          for (int i = 0; i < 4; i++) pv[n][i] = sa[n][i] * SC2_;
      }

      float mx[4];
      bool need = false;
#pragma unroll
      for (int i = 0; i < 4; i++) {
        float m = fmaxf(fmaxf(pv[0][i], pv[1][i]), fmaxf(pv[2][i], pv[3][i]));
        m = fmaxf(m, __shfl_xor(m, 1));
        m = fmaxf(m, __shfl_xor(m, 2));
        m = fmaxf(m, __shfl_xor(m, 4));
        m = fmaxf(m, __shfl_xor(m, 8));
        mx[i] = m;
        need = need || (m > m_i[i] + 8.0f);
      }
      if (__any(need)) {
#pragma unroll
        for (int i = 0; i < 4; i++) {
          float mn = fmaxf(m_i[i], mx[i]);
          float f = exp2f(m_i[i] - mn);
          m_i[i] = mn;
          l_i[i] *= f;
#pragma unroll
          for (int nf = 0; nf < 8; nf++) o[nf][i] *= f;
        }
      }

#pragma unroll
      for (int i = 0; i < 4; i++) {
        int q = 4 * lg + i;
        u16* prow = pw + q * 64;
#pragma unroll
        for (int n = 0; n < 4; n++) {
          float p = exp2f(pv[n][i] - m_i[i]);
          l_i[i] += p;
          int chn = ((n * 2 + (lr >> 3)) ^ (q & 7));
          prow[chn * 8 + (lr & 7)] = f2bf(p);
        }
      }
      asm volatile("s_waitcnt lgkmcnt(0)" ::: "memory");

      bfx8 pa[2];
#pragma unroll
      for (int ks = 0; ks < 2; ks++) {
        int cp = (4 * ks + lg) ^ (lr & 7);
        pa[ks] = *(const bfx8*)(pw + lr * 64 + cp * 8);
      }
      __builtin_amdgcn_s_setprio(1);
#pragma unroll
      for (int nf = 0; nf < 8; nf++) {
        int d = nf * 16 + lr;
        const u16* vrow = Vd + d * 64;
#pragma unroll
        for (int ks = 0; ks < 2; ks++) {
          int cv = (4 * ks + lg) ^ (d & 7);
          bfx8 vf = *(const bfx8*)(vrow + cv * 8);
          o[nf] = __builtin_amdgcn_mfma_f32_16x16x32_bf16(pa[ks], vf, o[nf], 0, 0, 0);
        }
      }
      __builtin_amdgcn_s_setprio(0);
      __syncthreads();
      cur ^= 1;
    }

    float inv[4];
#pragma unroll
    for (int i = 0; i < 4; i++) {
      float l = l_i[i];
      l += __shfl_xor(l, 1);
      l += __shfl_xor(l, 2);
      l += __shfl_xor(l, 4);
      l += __shfl_xor(l, 8);
      inv[i] = 1.0f / l;
    }
    u16* ob = Og + ((size_t)(b * T_ + qr0)) * DM + h * HD;
#pragma unroll
    for (int nf = 0; nf < 8; nf++)
#pragma unroll
      for (int i = 0; i < 4; i++)
        ob[(size_t)(4 * lg + i) * DM + nf * 16 + lr] = f2bf(o[nf][i] * inv[i]);
  }
}

// ---------------- launch ----------------
extern "C" void kernel_launch(void* const* d_in, const int* in_sizes, int n_in,
                              void* d_out, int out_size, void* d_ws, size_t ws_size,
                              hipStream_t stream) {
  const float* x = (const float*)d_in[0];
  const float* cosp = (const float*)d_in[2];
  const float* sinp = (const float*)d_in[3];
  const float* Wq = (const float*)d_in[4];
  const float* Wk = (const float*)d_in[5];
  const float* Wv = (const float*)d_in[6];
  const float* Wo = (const float*)d_in[7];
  const float* bo = (const float*)d_in[8];
  const float* gq = (const float*)d_in[9];
  const float* gk = (const float*)d_in[10];

  char* ws = (char*)d_ws;
  u16* xbf  = (u16*)(ws + 0);           // 16 MB
  u16* wqkv = (u16*)(ws + 16777216);    // 16 MB
  u16* wo   = (u16*)(ws + 33554432);    // 8 MB
  u16* qkv  = (u16*)(ws + 41943040);    // 32 MB
  u16* qb   = (u16*)(ws + 75497472);    // 16 MB
  u16* kb   = (u16*)(ws + 92274688);    // 8 MB
  u16* vt   = (u16*)(ws + 100663296);   // 8 MB
  u16* ab   = (u16*)(ws + 109051904);   // 16 MB
  float* out = (float*)d_out;

  k_cvt<<<8192, 256, 0, stream>>>(x, xbf, 8388608);
  k_cvt<<<4096, 256, 0, stream>>>(Wq, wqkv, 4194304);
  k_cvt<<<2048, 256, 0, stream>>>(Wk, wqkv + 4194304, 2097152);
  k_cvt<<<2048, 256, 0, stream>>>(Wv, wqkv + 6291456, 2097152);
  k_cvt<<<4096, 256, 0, stream>>>(Wo, wo, 4194304);

  k_gemm256<<<256, 512, 0, stream>>>(xbf, wqkv, qkv, 4096, 4096, 2048);
  k_qkpost<<<1536, 256, 0, stream>>>(qkv, cosp, sinp, gq, gk, qb, kb);
  k_vtr<<<512, 256, 0, stream>>>(qkv, vt);
  k_attn<<<512, 256, 0, stream>>>(qb, kb, vt, ab);
  k_gemm<true><<<512, 256, 0, stream>>>(ab, wo, out, bo, 4096, 2048, 2048);
}

// Round 5
// 248.809 us; speedup vs baseline: 1.5720x; 1.0531x over previous
//
#include <hip/hip_runtime.h>
#include <stdint.h>

#define B_ 2
#define T_ 2048
#define DM 2048
#define NH 16
#define NKV 8
#define HD 128
#define NQKV 4096
#define SC2_ 0.12753102765f  // (1/sqrt(128)) * log2(e)

typedef float fx4 __attribute__((ext_vector_type(4)));
typedef __bf16 bfx8 __attribute__((ext_vector_type(8)));
typedef unsigned short u16;
typedef unsigned int u32;

typedef __attribute__((address_space(1))) const void gas_t;
typedef __attribute__((address_space(3))) void las_t;

__device__ __forceinline__ u16 f2bf(float f) {
  u32 u = __float_as_uint(f);
  u = (u + 0x7fffu + ((u >> 16) & 1u)) >> 16;
  return (u16)u;
}

// async global->LDS, 16B per lane; lds arg must be wave-uniform base + lane*16
__device__ __forceinline__ void stage16(const void* g, void* l) {
  __builtin_amdgcn_global_load_lds((gas_t*)(uintptr_t)g, (las_t*)(uintptr_t)l,
                                   16, 0, 0);
}

// ---------------- fp32 -> bf16 convert ----------------
__global__ void k_cvt(const float* __restrict__ in, u16* __restrict__ out, int n) {
  int i = (blockIdx.x * blockDim.x + threadIdx.x) * 4;
  if (i + 3 < n) {
    float4 v = *(const float4*)(in + i);
    u32 w0 = (u32)f2bf(v.x) | ((u32)f2bf(v.y) << 16);
    u32 w1 = (u32)f2bf(v.z) | ((u32)f2bf(v.w) << 16);
    *(uint2*)(out + i) = make_uint2(w0, w1);
  }
}

// ======== 256x256 8-phase GEMM (T2+T3+T4+T5): C[M][N] = A[M][K] B[N][K]^T ========
__global__ __launch_bounds__(512, 2) void k_gemm256(const u16* __restrict__ A,
                                                    const u16* __restrict__ Bm,
                                                    u16* __restrict__ C,
                                                    int M, int N, int K) {
  __shared__ __align__(16) u16 As[2][2][256 * 32];
  __shared__ __align__(16) u16 Bs[2][2][256 * 32];
  const int nbn = N >> 8;
  const int bm = blockIdx.x / nbn, bn = blockIdx.x % nbn;
  const int tid = threadIdx.x;
  const int w = tid >> 6, lane = tid & 63;
  const int wm = w >> 2, wn = w & 3;
  const int lr = lane & 15, lg = lane >> 4;
  const int cw = (lg ^ ((lr >> 1) & 3)) * 8;
  const u16* Ab = A + (size_t)bm * 256 * K;
  const u16* Bb = Bm + (size_t)bn * 256 * K;
  const int NT = K >> 6;

  auto stage = [&](const u16* gb, u16* region, int tile, int kh) {
#pragma unroll
    for (int i = 0; i < 2; i++) {
      int q = tid + i * 512;
      int row = q >> 2, ch = q & 3;
      int sc = ch ^ ((row >> 1) & 3);
      stage16(gb + (size_t)row * K + tile * 64 + kh * 32 + sc * 8, region + q * 8);
    }
  };

  fx4 acc[8][4];
  const fx4 zero4 = {0.f, 0.f, 0.f, 0.f};
#pragma unroll
  for (int m = 0; m < 8; m++)
#pragma unroll
    for (int n = 0; n < 4; n++) acc[m][n] = zero4;

  stage(Ab, &As[0][0][0], 0, 0);
  stage(Bb, &Bs[0][0][0], 0, 0);
  stage(Ab, &As[0][1][0], 0, 1);
  stage(Bb, &Bs[0][1][0], 0, 1);
  stage(Ab, &As[1][0][0], 1, 0);
  stage(Bb, &Bs[1][0][0], 1, 0);
  asm volatile("s_waitcnt vmcnt(4)" ::: "memory");
  __builtin_amdgcn_s_barrier();

  const int arow = (wm * 128 + lr) * 32;
  const int brow = (wn * 64 + lr) * 32;
  bfx8 af[4], bf[4];

#pragma unroll 1
  for (int t = 0; t < NT; t++) {
    const u16* A0 = &As[t & 1][0][0];
    const u16* A1 = &As[t & 1][1][0];
    const u16* B0 = &Bs[t & 1][0][0];
    const u16* B1 = &Bs[t & 1][1][0];
    const int p1 = (t + 1) & 1, p2 = t & 1;

#pragma unroll
    for (int mi = 0; mi < 4; mi++) af[mi] = *(const bfx8*)(A0 + arow + mi * 512 + cw);
#pragma unroll
    for (int n = 0; n < 4; n++) bf[n] = *(const bfx8*)(B0 + brow + n * 512 + cw);
    if (t + 1 < NT) stage(Ab, &As[p1][1][0], t + 1, 1);
    __builtin_amdgcn_s_barrier();
    asm volatile("s_waitcnt lgkmcnt(0)" ::: "memory");
    __builtin_amdgcn_sched_barrier(0);
    __builtin_amdgcn_s_setprio(1);
#pragma unroll
    for (int mi = 0; mi < 4; mi++)
#pragma unroll
      for (int n = 0; n < 4; n++)
        acc[mi][n] = __builtin_amdgcn_mfma_f32_16x16x32_bf16(af[mi], bf[n], acc[mi][n], 0, 0, 0);
    __builtin_amdgcn_s_setprio(0);
    __builtin_amdgcn_s_barrier();

#pragma unroll
    for (int mi = 0; mi < 4; mi++)
      af[mi] = *(const bfx8*)(A0 + arow + 2048 + mi * 512 + cw);
    if (t + 1 < NT) stage(Bb, &Bs[p1][1][0], t + 1, 1);
    __builtin_amdgcn_s_barrier();
    asm volatile("s_waitcnt lgkmcnt(0)" ::: "memory");
    __builtin_amdgcn_sched_barrier(0);
    __builtin_amdgcn_s_setprio(1);
#pragma unroll
    for (int mi = 0; mi < 4; mi++)
#pragma unroll
      for (int n = 0; n < 4; n++)
        acc[4 + mi][n] = __builtin_amdgcn_mfma_f32_16x16x32_bf16(af[mi], bf[n], acc[4 + mi][n], 0, 0, 0);
    __builtin_amdgcn_s_setprio(0);
    __builtin_amdgcn_s_barrier();

#pragma unroll
    for (int mi = 0; mi < 4; mi++) af[mi] = *(const bfx8*)(A1 + arow + mi * 512 + cw);
#pragma unroll
    for (int n = 0; n < 4; n++) bf[n] = *(const bfx8*)(B1 + brow + n * 512 + cw);
    if (t + 2 < NT) stage(Ab, &As[p2][0][0], t + 2, 0);
    __builtin_amdgcn_s_barrier();
    asm volatile("s_waitcnt lgkmcnt(0)" ::: "memory");
    __builtin_amdgcn_sched_barrier(0);
    __builtin_amdgcn_s_setprio(1);
#pragma unroll
    for (int mi = 0; mi < 4; mi++)
#pragma unroll
      for (int n = 0; n < 4; n++)
        acc[mi][n] = __builtin_amdgcn_mfma_f32_16x16x32_bf16(af[mi], bf[n], acc[mi][n], 0, 0, 0);
    __builtin_amdgcn_s_setprio(0);
    __builtin_amdgcn_s_barrier();

#pragma unroll
    for (int mi = 0; mi < 4; mi++)
      af[mi] = *(const bfx8*)(A1 + arow + 2048 + mi * 512 + cw);
    if (t + 2 < NT) stage(Bb, &Bs[p2][0][0], t + 2, 0);
    __builtin_amdgcn_s_barrier();
    asm volatile("s_waitcnt lgkmcnt(0)" ::: "memory");
    __builtin_amdgcn_sched_barrier(0);
    __builtin_amdgcn_s_setprio(1);
#pragma unroll
    for (int mi = 0; mi < 4; mi++)
#pragma unroll
      for (int n = 0; n < 4; n++)
        acc[4 + mi][n] = __builtin_amdgcn_mfma_f32_16x16x32_bf16(af[mi], bf[n], acc[4 + mi][n], 0, 0, 0);
    __builtin_amdgcn_s_setprio(0);
    asm volatile("s_waitcnt vmcnt(4)" ::: "memory");
    __builtin_amdgcn_s_barrier();
  }

  const int r0 = bm * 256 + wm * 128, c0 = bn * 256 + wn * 64;
#pragma unroll
  for (int m = 0; m < 8; m++) {
#pragma unroll
    for (int n = 0; n < 4; n++) {
      int c = c0 + n * 16 + lr;
#pragma unroll
      for (int i = 0; i < 4; i++)
        C[(size_t)(r0 + m * 16 + lg * 4 + i) * N + c] = f2bf(acc[m][n][i]);
    }
  }
}

// ---------------- bf16 GEMM (128^2 m97-structure), used for out-proj ----------------
template <bool OUT_F32>
__global__ __launch_bounds__(256, 2) void k_gemm(const u16* __restrict__ A,
                                                 const u16* __restrict__ Bm,
                                                 void* __restrict__ Cv,
                                                 const float* __restrict__ bias,
                                                 int M, int N, int K) {
  __shared__ __align__(16) u16 As[128 * 32];
  __shared__ __align__(16) u16 Bs[128 * 32];
  const int nbn = N >> 7;
  const int bm = blockIdx.x / nbn, bn = blockIdx.x % nbn;
  const int tid = threadIdx.x;
  const int w = tid >> 6, lane = tid & 63;
  const int wr = w >> 1, wc = w & 1;
  const int lr = lane & 15, lg = lane >> 4;
  const u16* Ab = A + (size_t)bm * 128 * K;
  const u16* Bb = Bm + (size_t)bn * 128 * K;
  const int srow = lane >> 2, skc = (lane & 3) * 8;

  fx4 zero4 = {0.f, 0.f, 0.f, 0.f};
  fx4 acc[4][4];
#pragma unroll
  for (int m = 0; m < 4; m++)
#pragma unroll
    for (int n = 0; n < 4; n++) acc[m][n] = zero4;

  for (int k0 = 0; k0 < K; k0 += 32) {
#pragma unroll
    for (int t = 0; t < 2; t++) {
      int s = w + t * 4;
      stage16(Ab + (size_t)(s * 16 + srow) * K + k0 + skc, As + s * 512 + lane * 8);
      stage16(Bb + (size_t)(s * 16 + srow) * K + k0 + skc, Bs + s * 512 + lane * 8);
    }
    __syncthreads();
    bfx8 af[4], bfr[4];
#pragma unroll
    for (int m = 0; m < 4; m++)
      af[m] = *(const bfx8*)(As + (wr * 64 + m * 16 + lr) * 32 + lg * 8);
#pragma unroll
    for (int n = 0; n < 4; n++)
      bfr[n] = *(const bfx8*)(Bs + (wc * 64 + n * 16 + lr) * 32 + lg * 8);
#pragma unroll
    for (int m = 0; m < 4; m++)
#pragma unroll
      for (int n = 0; n < 4; n++)
        acc[m][n] = __builtin_amdgcn_mfma_f32_16x16x32_bf16(af[m], bfr[n], acc[m][n], 0, 0, 0);
    __syncthreads();
  }

  const int r0 = bm * 128 + wr * 64, c0 = bn * 128 + wc * 64;
#pragma unroll
  for (int m = 0; m < 4; m++) {
#pragma unroll
    for (int n = 0; n < 4; n++) {
      int c = c0 + n * 16 + lr;
#pragma unroll
      for (int i = 0; i < 4; i++) {
        int r = r0 + m * 16 + lg * 4 + i;
        if (OUT_F32) {
          ((float*)Cv)[(size_t)r * N + c] = acc[m][n][i] + bias[c];
        } else {
          ((u16*)Cv)[(size_t)r * N + c] = f2bf(acc[m][n][i]);
        }
      }
    }
  }
}

// ---------------- Q/K epilogue: rmsnorm + rope, relayout ----------------
__global__ __launch_bounds__(256) void k_qkpost(const u16* __restrict__ qkv,
                                                const float* __restrict__ cosp,
                                                const float* __restrict__ sinp,
                                                const float* __restrict__ gq,
                                                const float* __restrict__ gk,
                                                u16* __restrict__ Qo,
                                                u16* __restrict__ Ko) {
  int bi = blockIdx.x;
  int hh = bi % 24;
  int t64 = (bi / 24) % 32;
  int b = bi / 768;
  int tid = threadIdx.x;
  int j = tid >> 2, p = tid & 3;
  int t = t64 * 64 + j;
  bool isq = hh < 16;
  int colbase = isq ? hh * 128 : 2048 + (hh - 16) * 128;
  const u16* src = qkv + ((size_t)(b * T_ + t)) * NQKV + colbase + p * 32;

  float xv[32];
#pragma unroll
  for (int c = 0; c < 4; c++) {
    uint4 raw = *(const uint4*)(src + c * 8);
    u32 wd[4] = {raw.x, raw.y, raw.z, raw.w};
#pragma unroll
    for (int q2 = 0; q2 < 4; q2++) {
      xv[c * 8 + q2 * 2 + 0] = __uint_as_float(wd[q2] << 16);
      xv[c * 8 + q2 * 2 + 1] = __uint_as_float(wd[q2] & 0xffff0000u);
    }
  }
  float ss = 0.f;
#pragma unroll
  for (int i = 0; i < 32; i++) ss += xv[i] * xv[i];
  ss += __shfl_xor(ss, 1);
  ss += __shfl_xor(ss, 2);
  float rinv = rsqrtf(ss * (1.0f / 128.0f) + 1e-6f);
  const float* g = isq ? gq : gk;
  const float* cr = cosp + (size_t)t * 128 + p * 32;
  const float* sr = sinp + (size_t)t * 128 + p * 32;

  float ov[32];
#pragma unroll
  for (int i = 0; i < 32; i++) {
    float y = xv[i] * rinv * g[p * 32 + i];
    float oth = __shfl_xor(y, 2);
    float rot = (p < 2) ? -oth : oth;
    ov[i] = y * cr[i] + rot * sr[i];
  }

  uint4 pk[4];
#pragma unroll
  for (int c = 0; c < 4; c++) {
    u32 wd[4];
#pragma unroll
    for (int q2 = 0; q2 < 4; q2++)
      wd[q2] = (u32)f2bf(ov[c * 8 + q2 * 2]) | ((u32)f2bf(ov[c * 8 + q2 * 2 + 1]) << 16);
    pk[c] = make_uint4(wd[0], wd[1], wd[2], wd[3]);
  }

  if (isq) {
    u16* dst = Qo + (((size_t)(b * NH + hh)) * T_ + t) * HD + p * 32;
#pragma unroll
    for (int c = 0; c < 4; c++) *(uint4*)(dst + c * 8) = pk[c];
  } else {
    int hk = hh - 16;
    u16* dstrow = Ko + (((size_t)(b * NKV + hk)) * T_ + t) * HD;
#pragma unroll
    for (int c = 0; c < 4; c++) {
      int C = p * 4 + c;
      int Cs = C ^ (t & 7);  // XOR swizzle (16 chunks/row), matches attn read
      *(uint4*)(dstrow + Cs * 8) = pk[c];
    }
  }
}

// ---------------- V transpose: qkv[...,3072+] -> vt[b][hkv][d][t] ----------------
__global__ __launch_bounds__(256) void k_vtr(const u16* __restrict__ qkv,
                                             u16* __restrict__ vt) {
  __shared__ __align__(16) u16 sm[128 * 64];
  int bi = blockIdx.x;
  int hv = bi & 7;
  int t64 = (bi >> 3) & 31;
  int b = bi >> 8;
  int tid = threadIdx.x;
#pragma unroll
  for (int it = 0; it < 4; it++) {
    int idx = tid + it * 256;
    int tok = idx >> 4, c = idx & 15;
    uint4 raw = *(const uint4*)(qkv + ((size_t)(b * T_ + t64 * 64 + tok)) * NQKV +
                                3072 + hv * 128 + c * 8);
    u32 wd[4] = {raw.x, raw.y, raw.z, raw.w};
#pragma unroll
    for (int q2 = 0; q2 < 4; q2++) {
      sm[(c * 8 + q2 * 2 + 0) * 64 + tok] = (u16)(wd[q2] & 0xffffu);
      sm[(c * 8 + q2 * 2 + 1) * 64 + tok] = (u16)(wd[q2] >> 16);
    }
  }
  __syncthreads();
  int d = tid >> 1, half = tid & 1;
  size_t rowb = (((size_t)(b * NKV + hv)) * HD + d) * T_ + t64 * 64;
#pragma unroll
  for (int c = 0; c < 4; c++) {
    int cg = half * 4 + c;
    int cs = cg ^ (d & 7);
    u32 wd[4];
#pragma unroll
    for (int q2 = 0; q2 < 4; q2++) {
      u32 lo = sm[d * 64 + half * 32 + c * 8 + 2 * q2];
      u32 hi = sm[d * 64 + half * 32 + c * 8 + 2 * q2 + 1];
      wd[q2] = lo | (hi << 16);
    }
    *(uint4*)(vt + rowb + cs * 8) = make_uint4(wd[0], wd[1], wd[2], wd[3]);
  }
}

// ---------------- flash attention (causal, GQA rep=2) ----------------
// grid = B*NH*16 = 512 blocks, 512 thr (8 waves). Waves 0-3: q-tile z,
// waves 4-7: q-tile 31-z, sharing ONE K/V staging stream over chunks
// 0..31-z (tile z's chunks are a prefix). No-max softmax (scores bounded
// by rmsnorm: |s*log2e/sqrt(128)| <= 16.33). Raw barriers + counted vmcnt.
__global__ __launch_bounds__(512, 4) void k_attn(const u16* __restrict__ Qg,
                                                 const u16* __restrict__ Kg,
                                                 const u16* __restrict__ Vg,
                                                 u16* __restrict__ Og) {
  __shared__ __align__(16) u16 Ks[2][64 * 128];
  __shared__ __align__(16) u16 Vs[2][128 * 64];
  __shared__ __align__(16) u16 Ps[8][16 * 64];
  const int bi = blockIdx.x;
  const int zr = bi & 15, h = (bi >> 4) & 15, b = bi >> 8;
  const int z = b ? (15 - zr) : zr;  // pair heavy+light across the two grid halves
  const int hkv = h >> 1;
  const int tid = threadIdx.x, w = tid >> 6, lane = tid & 63;
  const int lr = lane & 15, lg = lane >> 4;
  const int zt = (w < 4) ? z : (31 - z);  // this wave's q-tile
  const int qr0 = zt * 64 + (w & 3) * 16;
  const int nch = 32 - z;   // shared chunk count (= tile 31-z's need)
  const int myl = zt + 1;   // active while ch < myl

  const u16* kb = Kg + ((size_t)(b * NKV + hkv)) * T_ * HD;
  const u16* vb = Vg + ((size_t)(b * NKV + hkv)) * HD * T_;
  u16* pw = &Ps[w][0];
  const fx4 zero4 = {0.f, 0.f, 0.f, 0.f};

  // 512 threads stage K[64][128] + V[128][64] (32KB): 4 x 16B per thread.
  // Each it covers 512*8 = 4096 elements -> LDS offset it*4096 (NOT 8192).
  auto stageKV = [&](int buf, int kv0) {
    u16* Kd = &Ks[buf][0];
    u16* Vd = &Vs[buf][0];
#pragma unroll
    for (int it = 0; it < 2; it++) {
      int r = it * 32 + (tid >> 4);
      stage16(kb + (size_t)(kv0 + r) * HD + (tid & 15) * 8, Kd + it * 4096 + tid * 8);
      int d = it * 64 + (tid >> 3);
      stage16(vb + (size_t)d * T_ + kv0 + (tid & 7) * 8, Vd + it * 4096 + tid * 8);
    }
  };

  const u16* qbase = Qg + (((size_t)(b * NH + h)) * T_ + qr0 + lr) * HD;
  bfx8 qf[4];
#pragma unroll
  for (int kk = 0; kk < 4; kk++) qf[kk] = *(const bfx8*)(qbase + kk * 32 + lg * 8);

  fx4 o[8];
#pragma unroll
  for (int nf = 0; nf < 8; nf++) o[nf] = zero4;
  float l_i[4] = {0.f, 0.f, 0.f, 0.f};

  stageKV(0, 0);
  asm volatile("s_waitcnt vmcnt(0)" ::: "memory");
  __builtin_amdgcn_s_barrier();
  int cur = 0;

#pragma unroll 1
  for (int ch = 0; ch < nch; ch++) {
    // issue next-chunk loads; wait only the CURRENT buffer's 4 loads (counted)
    if (ch + 1 < nch) {
      stageKV(cur ^ 1, (ch + 1) * 64);
      asm volatile("s_waitcnt vmcnt(4)" ::: "memory");
    } else {
      asm volatile("s_waitcnt vmcnt(0)" ::: "memory");
    }
    __builtin_amdgcn_s_barrier();

    if (ch < myl) {
      const u16* Kd = &Ks[cur][0];
      const u16* Vd = &Vs[cur][0];
      const int kv0 = ch * 64;
      const bool diag = (ch == zt);

      // ---- S = Q K^T (16q x 64kv) ----
      fx4 sa[4];
#pragma unroll
      for (int n = 0; n < 4; n++) sa[n] = zero4;
      __builtin_amdgcn_s_setprio(1);
#pragma unroll
      for (int n = 0; n < 4; n++) {
        const int kvl = n * 16 + lr;
        const u16* krow = Kd + kvl * 128;
#pragma unroll
        for (int kk = 0; kk < 4; kk++) {
          int cs = (kk * 4 + lg) ^ (kvl & 7);
          bfx8 kf = *(const bfx8*)(krow + cs * 8);
          sa[n] = __builtin_amdgcn_mfma_f32_16x16x32_bf16(qf[kk], kf, sa[n], 0, 0, 0);
        }
      }
      __builtin_amdgcn_s_setprio(0);

      // ---- no-max softmax: p = exp2(s*SC2), mask diagonal, per-lane l ----
#pragma unroll
      for (int i = 0; i < 4; i++) {
        const int q = 4 * lg + i;
        const int r = qr0 + q;
        u16* prow = pw + q * 64;
#pragma unroll
        for (int n = 0; n < 4; n++) {
          float p = exp2f(sa[n][i] * SC2_);
          if (diag) p = ((kv0 + n * 16 + lr) > r) ? 0.f : p;
          l_i[i] += p;
          int chn = ((n * 2 + (lr >> 3)) ^ (q & 7));
          prow[chn * 8 + (lr & 7)] = f2bf(p);
        }
      }
      asm volatile("s_waitcnt lgkmcnt(0)" ::: "memory");

      // ---- O += P V ----
      bfx8 pa[2];
#pragma unroll
      for (int ks = 0; ks < 2; ks++) {
        int cp = (4 * ks + lg) ^ (lr & 7);
        pa[ks] = *(const bfx8*)(pw + lr * 64 + cp * 8);
      }
      __builtin_amdgcn_s_setprio(1);
#pragma unroll
      for (int nf = 0; nf < 8; nf++) {
        int d = nf * 16 + lr;
        const u16* vrow = Vd + d * 64;
#pragma unroll
        for (int ks = 0; ks < 2; ks++) {
          int cv = (4 * ks + lg) ^ (d & 7);
          bfx8 vf = *(const bfx8*)(vrow + cv * 8);
          o[nf] = __builtin_amdgcn_mfma_f32_16x16x32_bf16(pa[ks], vf, o[nf], 0, 0, 0);
        }
      }
      __builtin_amdgcn_s_setprio(0);
    }
    __builtin_amdgcn_s_barrier();  // all readers done before buf is restaged
    cur ^= 1;
  }

  // ---- finalize: reduce per-lane l over the 16-lane row group ----
  float inv[4];
#pragma unroll
  for (int i = 0; i < 4; i++) {
    float l = l_i[i];
    l += __shfl_xor(l, 1);
    l += __shfl_xor(l, 2);
    l += __shfl_xor(l, 4);
    l += __shfl_xor(l, 8);
    inv[i] = 1.0f / l;
  }
  u16* ob = Og + ((size_t)(b * T_ + qr0)) * DM + h * HD;
#pragma unroll
  for (int nf = 0; nf < 8; nf++)
#pragma unroll
    for (int i = 0; i < 4; i++)
      ob[(size_t)(4 * lg + i) * DM + nf * 16 + lr] = f2bf(o[nf][i] * inv[i]);
}

// ---------------- launch ----------------
extern "C" void kernel_launch(void* const* d_in, const int* in_sizes, int n_in,
                              void* d_out, int out_size, void* d_ws, size_t ws_size,
                              hipStream_t stream) {
  const float* x = (const float*)d_in[0];
  const float* cosp = (const float*)d_in[2];
  const float* sinp = (const float*)d_in[3];
  const float* Wq = (const float*)d_in[4];
  const float* Wk = (const float*)d_in[5];
  const float* Wv = (const float*)d_in[6];
  const float* Wo = (const float*)d_in[7];
  const float* bo = (const float*)d_in[8];
  const float* gq = (const float*)d_in[9];
  const float* gk = (const float*)d_in[10];

  char* ws = (char*)d_ws;
  u16* xbf  = (u16*)(ws + 0);           // 16 MB
  u16* wqkv = (u16*)(ws + 16777216);    // 16 MB
  u16* wo   = (u16*)(ws + 33554432);    // 8 MB
  u16* qkv  = (u16*)(ws + 41943040);    // 32 MB
  u16* qb   = (u16*)(ws + 75497472);    // 16 MB
  u16* kb   = (u16*)(ws + 92274688);    // 8 MB
  u16* vt   = (u16*)(ws + 100663296);   // 8 MB
  u16* ab   = (u16*)(ws + 109051904);   // 16 MB
  float* out = (float*)d_out;

  k_cvt<<<8192, 256, 0, stream>>>(x, xbf, 8388608);
  k_cvt<<<4096, 256, 0, stream>>>(Wq, wqkv, 4194304);
  k_cvt<<<2048, 256, 0, stream>>>(Wk, wqkv + 4194304, 2097152);
  k_cvt<<<2048, 256, 0, stream>>>(Wv, wqkv + 6291456, 2097152);
  k_cvt<<<4096, 256, 0, stream>>>(Wo, wo, 4194304);

  k_gemm256<<<256, 512, 0, stream>>>(xbf, wqkv, qkv, 4096, 4096, 2048);
  k_qkpost<<<1536, 256, 0, stream>>>(qkv, cosp, sinp, gq, gk, qb, kb);
  k_vtr<<<512, 256, 0, stream>>>(qkv, vt);
  k_attn<<<512, 512, 0, stream>>>(qb, kb, vt, ab);
  k_gemm<true><<<512, 256, 0, stream>>>(ab, wo, out, bo, 4096, 2048, 2048);
}